// Round 3
// baseline (315.367 us; speedup 1.0000x reference)
//
#include <hip/hip_runtime.h>
#include <hip/hip_bf16.h>

#define B_ 8
#define C_ 64
#define H_ 128
#define W_ 128
#define HW_ (H_ * W_)

typedef __attribute__((ext_vector_type(8))) short short8;
typedef __attribute__((ext_vector_type(4))) float float4v;
typedef _Float16 f16x2 __attribute__((ext_vector_type(2)));

static __device__ inline unsigned bfbits(float f) {
    __hip_bfloat16 h = __float2bfloat16(f);
    unsigned short s;
    __builtin_memcpy(&s, &h, 2);
    return (unsigned)s;
}

// f16x2 pair-dot with f32 accumulate (v_dot2_f32_f16).
static __device__ inline float dot2(unsigned a, unsigned b, float c) {
    f16x2 ha, hb;
    __builtin_memcpy(&ha, &a, 4);
    __builtin_memcpy(&hb, &b, 4);
#if __has_builtin(__builtin_amdgcn_fdot2)
    return __builtin_amdgcn_fdot2(ha, hb, c, false);
#else
    return fmaf((float)ha.x, (float)hb.x, fmaf((float)ha.y, (float)hb.y, c));
#endif
}

static __device__ inline float2 up2(unsigned u) {
    f16x2 h;
    __builtin_memcpy(&h, &u, 4);
    return make_float2((float)h.x, (float)h.y);
}

// async global->LDS, 16B per lane, LDS dest = wave-uniform base + lane*16
static __device__ __attribute__((always_inline)) void glds16(const void* g, void* l) {
#if __has_builtin(__builtin_amdgcn_global_load_lds)
    __builtin_amdgcn_global_load_lds(
        (const __attribute__((address_space(1))) void*)g,
        (__attribute__((address_space(3))) void*)l, 16, 0, 0);
#else
    *(uint4*)l = *(const uint4*)g;
#endif
}

// ---------------------------------------------------------------------------
// K0: repack W1|W2|W3 (fp32 [o][c]) into bf16 MFMA B-fragments, SPLIT hi/lo
// (unchanged; proj GEMM keeps its fp32-grade 3-term split).
// ---------------------------------------------------------------------------
__global__ void repack_w(const float* __restrict__ w1, const float* __restrict__ w2,
                         const float* __restrict__ w3,
                         unsigned short* __restrict__ wBhi, unsigned short* __restrict__ wBlo)
{
    const int i = blockIdx.x * 256 + threadIdx.x;
    if (i >= 12288) return;
    const int j = i & 7, lane = (i >> 3) & 63, ks = (i >> 9) & 1, nt = i >> 10;
    const int o = nt * 16 + (lane & 15);
    const int c = ks * 32 + (lane >> 4) * 8 + j;
    const float* wsel = (o < 64) ? w1 : (o < 128) ? w2 : w3;
    const float w = wsel[(o & 63) * 64 + c];
    const unsigned hb = bfbits(w);
    wBhi[i] = (unsigned short)hb;
    wBlo[i] = (unsigned short)bfbits(w - __uint_as_float(hb << 16));
}

// ---------------------------------------------------------------------------
// K1: QKV projection, same math (3-term bf16 split MFMA, fp32 accum), but
// 512-thread blocks (2m x 4n waves, 3 n-tiles/wave): per-wave VGPR ~105
// (acc 48 + A 32 + B 8), capped 128 via launch_bounds(512,4) -> 4 waves/SIMD
// (was 2) for 2x latency hiding on the 64 scalar x-loads/thread.
// q, k, v stored fp16, layout [b][chunk4][HW][16].
// ---------------------------------------------------------------------------
__global__ __launch_bounds__(512, 4) void proj_qkv(
    const float* __restrict__ x,
    const unsigned short* __restrict__ wBhi, const unsigned short* __restrict__ wBlo,
    _Float16* __restrict__ q, _Float16* __restrict__ k, _Float16* __restrict__ v)
{
    const int b = blockIdx.y;
    const int px0 = blockIdx.x * 128;
    const int t = threadIdx.x;
    const int lane = t & 63;
    const int wave = t >> 6;                 // 0..7
    const int wave_m = wave & 1, wave_n = wave >> 1;   // 2 x 4
    const int n = lane & 15, kg = lane >> 4;

    float4v acc[3][4];
    #pragma unroll
    for (int tnt = 0; tnt < 3; ++tnt)
        #pragma unroll
        for (int mt = 0; mt < 4; ++mt)
            acc[tnt][mt] = (float4v){0.f, 0.f, 0.f, 0.f};

    const float* xb = x + (size_t)b * C_ * HW_;
    const int pxl = px0 + wave_m * 64 + n;

    #pragma unroll
    for (int ks = 0; ks < 2; ++ks) {
        short8 ahi[4], alo[4];
        #pragma unroll
        for (int mt = 0; mt < 4; ++mt) {
            #pragma unroll
            for (int j = 0; j < 8; ++j) {
                const int c = ks * 32 + kg * 8 + j;
                const float f = xb[(size_t)c * HW_ + pxl + mt * 16];
                const unsigned hb = bfbits(f);
                ahi[mt][j] = (short)hb;
                alo[mt][j] = (short)bfbits(f - __uint_as_float(hb << 16));
            }
        }
        #pragma unroll
        for (int tnt = 0; tnt < 3; ++tnt) {
            const int gnt = wave_n * 3 + tnt;          // 0..11 global n-tile
            const size_t bidx = (((size_t)gnt * 2 + ks) * 64 + lane) * 8;
            short8 bh, bl;
            {
                const uint4 uh = *(const uint4*)(wBhi + bidx);
                const uint4 ul = *(const uint4*)(wBlo + bidx);
                __builtin_memcpy(&bh, &uh, 16);
                __builtin_memcpy(&bl, &ul, 16);
            }
            #pragma unroll
            for (int mt = 0; mt < 4; ++mt) {
                acc[tnt][mt] = __builtin_amdgcn_mfma_f32_16x16x32_bf16(
                    ahi[mt], bh, acc[tnt][mt], 0, 0, 0);
                acc[tnt][mt] = __builtin_amdgcn_mfma_f32_16x16x32_bf16(
                    alo[mt], bh, acc[tnt][mt], 0, 0, 0);
                acc[tnt][mt] = __builtin_amdgcn_mfma_f32_16x16x32_bf16(
                    ahi[mt], bl, acc[tnt][mt], 0, 0, 0);
            }
        }
    }

    // epilogue: D col = n (output o), row m = kg*4 + reg (pixel); fp16 stores
    #pragma unroll
    for (int tnt = 0; tnt < 3; ++tnt) {
        const int gnt = wave_n * 3 + tnt;              // wave-uniform
        _Float16* base = (gnt < 4) ? q : (gnt < 8) ? k : v;
        const int chunk = gnt & 3;
        #pragma unroll
        for (int mt = 0; mt < 4; ++mt) {
            const int pxm = px0 + wave_m * 64 + mt * 16 + kg * 4;
            const float4v d = acc[tnt][mt];
            _Float16* p = base + (((size_t)b * 4 + chunk) * HW_ + pxm) * 16 + n;
            #pragma unroll
            for (int r = 0; r < 4; ++r) p[(size_t)r * 16] = (_Float16)d[r];
        }
    }
}

// ---------------------------------------------------------------------------
// K2: fused local attention, fp16, async-pipelined staging.
// Occupancy is GRID-capped (512 blocks = 2/CU, 8 waves/CU) -> the lever is
// hiding stage latency, not occupancy. Staging now uses global_load_lds
// (no VGPR round-trip) and each half-tile's loads are ISSUED before the
// compute they fly under; the barrier after finds them mostly arrived:
//   issue k0 | bar | issue k1, score0 | bar | issue v0, score1+softmax |
//   bar | issue v1, weight0 | bar | weight1.
// LDS: 8 planes x 2048 words (plane = 484 halo px x 4 words, padded to 512
// cells) = 64 KB. glds dest must be linear: cell = round*256 + tid, so per
// wave 64 consecutive cells, per-lane GLOBAL address carries the halo
// coords. Border blocks pre-zero the tile once (OOB cells identical for k
// and v phases). grid (8,8,8), 256 thr.
// ---------------------------------------------------------------------------
#define PW_ 2048                // words per plane (512 cells of 16B)

static __device__ inline void stage_half(const _Float16* __restrict__ src, int b,
                                         float* tile, int p8base, int wv,
                                         bool okA, size_t gofsA, bool okB, size_t gofsB)
{
    #pragma unroll
    for (int pp = 0; pp < 4; ++pp) {
        const int p8 = p8base + pp;
        const _Float16* gp = src + ((size_t)(b * 4 + (p8 >> 1)) * HW_) * 16 + (p8 & 1) * 8;
        float* lp = tile + p8 * PW_ + wv * 256;       // wave-uniform LDS base
        if (okA) glds16(gp + gofsA * 16, lp);
        if (okB) glds16(gp + gofsB * 16, lp + 1024);  // round-1 cells at +256
    }
}

static __device__ inline void score_half(const float* tp, const uint4* qv,
                                         float* sc, int ph, int pw)
{
    #pragma unroll
    for (int dh = 0; dh < 7; ++dh) {
        #pragma unroll
        for (int dw = 0; dw < 7; ++dw) {
            const int np = ((ph + dh) * 22 + (pw + dw)) * 4;
            float s0 = 0.f, s1 = 0.f, s2 = 0.f, s3 = 0.f;
            #pragma unroll
            for (int pp = 0; pp < 4; ++pp) {
                const uint4 u = *(const uint4*)(tp + pp * PW_ + np);
                s0 = dot2(qv[pp].x, u.x, s0);
                s1 = dot2(qv[pp].y, u.y, s1);
                s2 = dot2(qv[pp].z, u.z, s2);
                s3 = dot2(qv[pp].w, u.w, s3);
            }
            sc[dh * 7 + dw] += (s0 + s1) + (s2 + s3);
        }
    }
}

static __device__ inline void weight_half(const float* tp, const float* sc,
                                          float* outb, size_t px, int ph, int pw)
{
    float acc[32];
    #pragma unroll
    for (int c = 0; c < 32; ++c) acc[c] = 0.f;
    #pragma unroll
    for (int dh = 0; dh < 7; ++dh) {
        #pragma unroll
        for (int dw = 0; dw < 7; ++dw) {
            const float wgt = sc[dh * 7 + dw];
            const int np = ((ph + dh) * 22 + (pw + dw)) * 4;
            #pragma unroll
            for (int pp = 0; pp < 4; ++pp) {
                const uint4 u = *(const uint4*)(tp + pp * PW_ + np);
                const int a = pp * 8;
                float2 f;
                f = up2(u.x); acc[a + 0] = fmaf(wgt, f.x, acc[a + 0]);
                              acc[a + 1] = fmaf(wgt, f.y, acc[a + 1]);
                f = up2(u.y); acc[a + 2] = fmaf(wgt, f.x, acc[a + 2]);
                              acc[a + 3] = fmaf(wgt, f.y, acc[a + 3]);
                f = up2(u.z); acc[a + 4] = fmaf(wgt, f.x, acc[a + 4]);
                              acc[a + 5] = fmaf(wgt, f.y, acc[a + 5]);
                f = up2(u.w); acc[a + 6] = fmaf(wgt, f.x, acc[a + 6]);
                              acc[a + 7] = fmaf(wgt, f.y, acc[a + 7]);
            }
        }
    }
    #pragma unroll
    for (int pp = 0; pp < 4; ++pp)
        #pragma unroll
        for (int j = 0; j < 8; ++j)
            outb[(size_t)(pp * 8 + j) * HW_ + px] = acc[pp * 8 + j];
}

__global__ __launch_bounds__(256, 2) void local_attn(
    const _Float16* __restrict__ q, const _Float16* __restrict__ k,
    const _Float16* __restrict__ v, float* __restrict__ out)
{
    __shared__ float tile[8 * PW_];                 // 64 KB
    const int b = blockIdx.z, h0 = blockIdx.y * 16, w0 = blockIdx.x * 16;
    const int t = threadIdx.x;
    const int pw = t & 15, ph = t >> 4, wv = t >> 6;
    const size_t px = (size_t)(h0 + ph) * W_ + (w0 + pw);

    // staging coords: cell = round*256 + t; pix = cell; halo 22x22
    const int pixA = t, pixB = 256 + t;
    const int rA = pixA / 22, cA = pixA - rA * 22;
    const int rB = pixB / 22, cB = pixB - rB * 22;
    const int ghA = h0 + rA - 3, gwA = w0 + cA - 3;
    const int ghB = h0 + rB - 3, gwB = w0 + cB - 3;
    const bool okA = (ghA >= 0 && ghA < H_ && gwA >= 0 && gwA < W_);
    const bool okB = (pixB < 484) && (ghB >= 0 && ghB < H_ && gwB >= 0 && gwB < W_);
    const size_t gofsA = (size_t)(ghA * W_ + gwA);
    const size_t gofsB = (size_t)(ghB * W_ + gwB);

    // border blocks: zero tile so OOB halo cells read 0 (covers k AND v)
    if (h0 == 0 || h0 == H_ - 16 || w0 == 0 || w0 == W_ - 16) {
        #pragma unroll
        for (int i = 0; i < 16; ++i)
            *(uint4*)(tile + (i * 256 + t) * 4) = make_uint4(0u, 0u, 0u, 0u);
        __syncthreads();
    }

    // issue k half0 (planes 0-3); q loads fly alongside
    stage_half(k, b, tile, 0, wv, okA, gofsA, okB, gofsB);
    uint4 qv[8];
    #pragma unroll
    for (int c8 = 0; c8 < 8; ++c8)
        qv[c8] = *(const uint4*)(q + (((size_t)b * 4 + (c8 >> 1)) * HW_ + px) * 16 + (c8 & 1) * 8);
    __syncthreads();                                // k half0 resident

    stage_half(k, b, tile, 4, wv, okA, gofsA, okB, gofsB);   // flies under score0
    float sc[49];
    #pragma unroll
    for (int i = 0; i < 49; ++i) sc[i] = 0.f;
    score_half(tile, qv, sc, ph, pw);
    __syncthreads();                                // k half1 resident

    stage_half(v, b, tile, 0, wv, okA, gofsA, okB, gofsB);   // flies under score1
    score_half(tile + 4 * PW_, qv + 4, sc, ph, pw);

    // softmax over 49
    float m = sc[0];
    #pragma unroll
    for (int i = 1; i < 49; ++i) m = fmaxf(m, sc[i]);
    float s = 0.f;
    #pragma unroll
    for (int i = 0; i < 49; ++i) { sc[i] = __expf(sc[i] - m); s += sc[i]; }
    const float inv = 1.f / s;
    #pragma unroll
    for (int i = 0; i < 49; ++i) sc[i] *= inv;
    __syncthreads();                                // v half0 resident

    stage_half(v, b, tile, 4, wv, okA, gofsA, okB, gofsB);   // flies under weight0
    weight_half(tile, sc, out + (size_t)b * 64 * HW_, px, ph, pw);
    __syncthreads();                                // v half1 resident
    weight_half(tile + 4 * PW_, sc, out + ((size_t)b * 64 + 32) * HW_, px, ph, pw);
}

extern "C" void kernel_launch(void* const* d_in, const int* in_sizes, int n_in,
                              void* d_out, int out_size, void* d_ws, size_t ws_size,
                              hipStream_t stream) {
    const float* x  = (const float*)d_in[0];
    const float* w1 = (const float*)d_in[1];
    const float* w2 = (const float*)d_in[2];
    const float* w3 = (const float*)d_in[3];

    const size_t NE = (size_t)B_ * 4 * HW_ * 16;   // 8388608 elems per tensor
    _Float16* q = (_Float16*)d_ws;
    _Float16* k = q + NE;
    _Float16* v = k + NE;
    unsigned short* wBhi = (unsigned short*)(v + NE);  // 12288 ushorts
    unsigned short* wBlo = wBhi + 12288;
    float* o = (float*)d_out;

    repack_w<<<dim3(48), 256, 0, stream>>>(w1, w2, w3, wBhi, wBlo);
    proj_qkv<<<dim3(HW_ / 128, B_), 512, 0, stream>>>(x, wBhi, wBlo, q, k, v);
    local_attn<<<dim3(W_ / 16, H_ / 16, B_), 256, 0, stream>>>(q, k, v, o);
}

// Round 4
// 154.368 us; speedup vs baseline: 2.0430x; 2.0430x over previous
//
#include <hip/hip_runtime.h>
#include <hip/hip_bf16.h>

#define B_ 8
#define C_ 64
#define H_ 128
#define W_ 128
#define HW_ (H_ * W_)

typedef __attribute__((ext_vector_type(8))) short short8;
typedef __attribute__((ext_vector_type(4))) float float4v;
typedef _Float16 f16x2 __attribute__((ext_vector_type(2)));

static __device__ inline unsigned bfbits(float f) {
    __hip_bfloat16 h = __float2bfloat16(f);
    unsigned short s;
    __builtin_memcpy(&s, &h, 2);
    return (unsigned)s;
}

// f16x2 pair-dot with f32 accumulate (v_dot2_f32_f16).
static __device__ inline float dot2(unsigned a, unsigned b, float c) {
    f16x2 ha, hb;
    __builtin_memcpy(&ha, &a, 4);
    __builtin_memcpy(&hb, &b, 4);
#if __has_builtin(__builtin_amdgcn_fdot2)
    return __builtin_amdgcn_fdot2(ha, hb, c, false);
#else
    return fmaf((float)ha.x, (float)hb.x, fmaf((float)ha.y, (float)hb.y, c));
#endif
}

static __device__ inline float2 up2(unsigned u) {
    f16x2 h;
    __builtin_memcpy(&h, &u, 4);
    return make_float2((float)h.x, (float)h.y);
}

// ---------------------------------------------------------------------------
// K0: repack W1|W2|W3 (fp32 [o][c]) into bf16 MFMA B-fragments, SPLIT hi/lo.
// ---------------------------------------------------------------------------
__global__ void repack_w(const float* __restrict__ w1, const float* __restrict__ w2,
                         const float* __restrict__ w3,
                         unsigned short* __restrict__ wBhi, unsigned short* __restrict__ wBlo)
{
    const int i = blockIdx.x * 256 + threadIdx.x;
    if (i >= 12288) return;
    const int j = i & 7, lane = (i >> 3) & 63, ks = (i >> 9) & 1, nt = i >> 10;
    const int o = nt * 16 + (lane & 15);
    const int c = ks * 32 + (lane >> 4) * 8 + j;
    const float* wsel = (o < 64) ? w1 : (o < 128) ? w2 : w3;
    const float w = wsel[(o & 63) * 64 + c];
    const unsigned hb = bfbits(w);
    wBhi[i] = (unsigned short)hb;
    wBlo[i] = (unsigned short)bfbits(w - __uint_as_float(hb << 16));
}

// ---------------------------------------------------------------------------
// K1: QKV projection (R3 version, correctness-proven): 512-thread blocks,
// 2m x 4n waves, 3 n-tiles/wave; per-wave VGPR ~105, launch_bounds(512,4)
// -> 4 waves/SIMD (2x the latency hiding of the 256-thread version) for the
// 64 scalar x-loads/thread. Math unchanged: 3-term bf16 split MFMA, fp32 acc.
// q, k, v stored fp16, layout [b][chunk4][HW][16].
// ---------------------------------------------------------------------------
__global__ __launch_bounds__(512, 4) void proj_qkv(
    const float* __restrict__ x,
    const unsigned short* __restrict__ wBhi, const unsigned short* __restrict__ wBlo,
    _Float16* __restrict__ q, _Float16* __restrict__ k, _Float16* __restrict__ v)
{
    const int b = blockIdx.y;
    const int px0 = blockIdx.x * 128;
    const int t = threadIdx.x;
    const int lane = t & 63;
    const int wave = t >> 6;                 // 0..7
    const int wave_m = wave & 1, wave_n = wave >> 1;   // 2 x 4
    const int n = lane & 15, kg = lane >> 4;

    float4v acc[3][4];
    #pragma unroll
    for (int tnt = 0; tnt < 3; ++tnt)
        #pragma unroll
        for (int mt = 0; mt < 4; ++mt)
            acc[tnt][mt] = (float4v){0.f, 0.f, 0.f, 0.f};

    const float* xb = x + (size_t)b * C_ * HW_;
    const int pxl = px0 + wave_m * 64 + n;

    #pragma unroll
    for (int ks = 0; ks < 2; ++ks) {
        short8 ahi[4], alo[4];
        #pragma unroll
        for (int mt = 0; mt < 4; ++mt) {
            #pragma unroll
            for (int j = 0; j < 8; ++j) {
                const int c = ks * 32 + kg * 8 + j;
                const float f = xb[(size_t)c * HW_ + pxl + mt * 16];
                const unsigned hb = bfbits(f);
                ahi[mt][j] = (short)hb;
                alo[mt][j] = (short)bfbits(f - __uint_as_float(hb << 16));
            }
        }
        #pragma unroll
        for (int tnt = 0; tnt < 3; ++tnt) {
            const int gnt = wave_n * 3 + tnt;          // 0..11 global n-tile
            const size_t bidx = (((size_t)gnt * 2 + ks) * 64 + lane) * 8;
            short8 bh, bl;
            {
                const uint4 uh = *(const uint4*)(wBhi + bidx);
                const uint4 ul = *(const uint4*)(wBlo + bidx);
                __builtin_memcpy(&bh, &uh, 16);
                __builtin_memcpy(&bl, &ul, 16);
            }
            #pragma unroll
            for (int mt = 0; mt < 4; ++mt) {
                acc[tnt][mt] = __builtin_amdgcn_mfma_f32_16x16x32_bf16(
                    ahi[mt], bh, acc[tnt][mt], 0, 0, 0);
                acc[tnt][mt] = __builtin_amdgcn_mfma_f32_16x16x32_bf16(
                    alo[mt], bh, acc[tnt][mt], 0, 0, 0);
                acc[tnt][mt] = __builtin_amdgcn_mfma_f32_16x16x32_bf16(
                    ahi[mt], bl, acc[tnt][mt], 0, 0, 0);
            }
        }
    }

    // epilogue: D col = n (output o), row m = kg*4 + reg (pixel); fp16 stores
    #pragma unroll
    for (int tnt = 0; tnt < 3; ++tnt) {
        const int gnt = wave_n * 3 + tnt;              // wave-uniform
        _Float16* base = (gnt < 4) ? q : (gnt < 8) ? k : v;
        const int chunk = gnt & 3;
        #pragma unroll
        for (int mt = 0; mt < 4; ++mt) {
            const int pxm = px0 + wave_m * 64 + mt * 16 + kg * 4;
            const float4v d = acc[tnt][mt];
            _Float16* p = base + (((size_t)b * 4 + chunk) * HW_ + pxm) * 16 + n;
            #pragma unroll
            for (int r = 0; r < 4; ++r) p[(size_t)r * 16] = (_Float16)d[r];
        }
    }
}

// ---------------------------------------------------------------------------
// K2: fused local attention — EXACT R2 kernel (known-good 55.7 us).
// R3 lesson (2nd spill incident): merging staging/score/softmax/weight into
// one straight-line region with global_load_lds makes qv[32]+sc[49]+acc[32]
// concurrently live -> ~300B/thread scratch (WRITE_SIZE 44->337MB, dur 4x).
// Phase separation + the unroll-1 two-pass phase 2 IS the register budget.
// Single resident 60.8KB tile: 8 uint4-planes of 484 halo px, stride 1944
// words. Phase 1: q in 32 VGPRs, dot2 scores. Phase 2: two 32-channel
// passes. 3 barriers. grid (8,8,8), 2 blocks/CU.
// ---------------------------------------------------------------------------
#define HP_ 484                 // 22*22 halo pixels
#define PL_ 1944                // words per uint4-plane (484*4 + 8 pad)

__global__ __launch_bounds__(256, 2) void local_attn(
    const _Float16* __restrict__ q, const _Float16* __restrict__ k,
    const _Float16* __restrict__ v, float* __restrict__ out)
{
    __shared__ float tile[8 * PL_];
    const int b = blockIdx.z, h0 = blockIdx.y * 16, w0 = blockIdx.x * 16;
    const int t = threadIdx.x;
    const int pw = t & 15, ph = t >> 4;
    const size_t px = (size_t)(h0 + ph) * W_ + (w0 + pw);

    // q for own pixel: 4 chunks x 2 halves = 64 f16 in 8 uint4 (32 VGPR)
    uint4 qv[8];
    #pragma unroll
    for (int c8 = 0; c8 < 8; ++c8)
        qv[c8] = *(const uint4*)(q + (((size_t)b * 4 + (c8 >> 1)) * HW_ + px) * 16 + (c8 & 1) * 8);

    // ---- stage all of k (fp16, 8 planes) ----
    for (int i = t; i < HP_ * 8; i += 256) {
        const int pix = i >> 3, c8 = i & 7;
        const int r = pix / 22, cl = pix - r * 22;
        const int gh = h0 + r - 3, gw = w0 + cl - 3;
        uint4 val = make_uint4(0u, 0u, 0u, 0u);
        if (gh >= 0 && gh < H_ && gw >= 0 && gw < W_)
            val = *(const uint4*)(k + (((size_t)b * 4 + (c8 >> 1)) * HW_ +
                                       (size_t)gh * W_ + gw) * 16 + (c8 & 1) * 8);
        *(uint4*)(tile + c8 * PL_ + pix * 4) = val;
    }
    __syncthreads();

    // ---- phase 1: scores via dot2 ----
    float sc[49];
    #pragma unroll
    for (int dh = 0; dh < 7; ++dh) {
        #pragma unroll
        for (int dw = 0; dw < 7; ++dw) {
            const int np = ((ph + dh) * 22 + (pw + dw)) * 4;
            float s0 = 0.f, s1 = 0.f, s2 = 0.f, s3 = 0.f;
            #pragma unroll
            for (int p8 = 0; p8 < 8; ++p8) {
                const uint4 u = *(const uint4*)(tile + p8 * PL_ + np);
                s0 = dot2(qv[p8].x, u.x, s0);
                s1 = dot2(qv[p8].y, u.y, s1);
                s2 = dot2(qv[p8].z, u.z, s2);
                s3 = dot2(qv[p8].w, u.w, s3);
            }
            sc[dh * 7 + dw] = (s0 + s1) + (s2 + s3);
        }
    }

    // ---- softmax over 49 ----
    float m = sc[0];
    #pragma unroll
    for (int i = 1; i < 49; ++i) m = fmaxf(m, sc[i]);
    float s = 0.f;
    #pragma unroll
    for (int i = 0; i < 49; ++i) { sc[i] = __expf(sc[i] - m); s += sc[i]; }
    const float inv = 1.f / s;
    #pragma unroll
    for (int i = 0; i < 49; ++i) sc[i] *= inv;

    __syncthreads();            // all phase-1 reads done before overwrite

    // ---- stage all of v (fp16, same layout) ----
    for (int i = t; i < HP_ * 8; i += 256) {
        const int pix = i >> 3, c8 = i & 7;
        const int r = pix / 22, cl = pix - r * 22;
        const int gh = h0 + r - 3, gw = w0 + cl - 3;
        uint4 val = make_uint4(0u, 0u, 0u, 0u);
        if (gh >= 0 && gh < H_ && gw >= 0 && gw < W_)
            val = *(const uint4*)(v + (((size_t)b * 4 + (c8 >> 1)) * HW_ +
                                       (size_t)gh * W_ + gw) * 16 + (c8 & 1) * 8);
        *(uint4*)(tile + c8 * PL_ + pix * 4) = val;
    }
    __syncthreads();

    // ---- phase 2: weighting, two 32-channel passes (no concurrent acc[64]) ----
    #pragma unroll 1
    for (int g = 0; g < 2; ++g) {
        float acc[32];
        #pragma unroll
        for (int c = 0; c < 32; ++c) acc[c] = 0.f;
        #pragma unroll
        for (int dh = 0; dh < 7; ++dh) {
            #pragma unroll
            for (int dw = 0; dw < 7; ++dw) {
                const float wgt = sc[dh * 7 + dw];
                const int np = ((ph + dh) * 22 + (pw + dw)) * 4;
                #pragma unroll
                for (int pp = 0; pp < 4; ++pp) {
                    const uint4 u = *(const uint4*)(tile + (g * 4 + pp) * PL_ + np);
                    const int a = pp * 8;
                    float2 f;
                    f = up2(u.x); acc[a + 0] = fmaf(wgt, f.x, acc[a + 0]);
                                  acc[a + 1] = fmaf(wgt, f.y, acc[a + 1]);
                    f = up2(u.y); acc[a + 2] = fmaf(wgt, f.x, acc[a + 2]);
                                  acc[a + 3] = fmaf(wgt, f.y, acc[a + 3]);
                    f = up2(u.z); acc[a + 4] = fmaf(wgt, f.x, acc[a + 4]);
                                  acc[a + 5] = fmaf(wgt, f.y, acc[a + 5]);
                    f = up2(u.w); acc[a + 6] = fmaf(wgt, f.x, acc[a + 6]);
                                  acc[a + 7] = fmaf(wgt, f.y, acc[a + 7]);
                }
            }
        }
        // store this pass's 32 channels: [b][64][HW], coalesced per channel
        #pragma unroll
        for (int pp = 0; pp < 4; ++pp) {
            const int p8 = g * 4 + pp;
            const int ch0 = (p8 >> 1) * 16 + (p8 & 1) * 8;
            #pragma unroll
            for (int j = 0; j < 8; ++j)
                out[((size_t)b * 64 + ch0 + j) * HW_ + px] = acc[pp * 8 + j];
        }
    }
}

extern "C" void kernel_launch(void* const* d_in, const int* in_sizes, int n_in,
                              void* d_out, int out_size, void* d_ws, size_t ws_size,
                              hipStream_t stream) {
    const float* x  = (const float*)d_in[0];
    const float* w1 = (const float*)d_in[1];
    const float* w2 = (const float*)d_in[2];
    const float* w3 = (const float*)d_in[3];

    const size_t NE = (size_t)B_ * 4 * HW_ * 16;   // 8388608 elems per tensor
    _Float16* q = (_Float16*)d_ws;
    _Float16* k = q + NE;
    _Float16* v = k + NE;
    unsigned short* wBhi = (unsigned short*)(v + NE);  // 12288 ushorts
    unsigned short* wBlo = wBhi + 12288;
    float* o = (float*)d_out;

    repack_w<<<dim3(48), 256, 0, stream>>>(w1, w2, w3, wBhi, wBlo);
    proj_qkv<<<dim3(HW_ / 128, B_), 512, 0, stream>>>(x, wBhi, wBlo, q, k, v);
    local_attn<<<dim3(W_ / 16, H_ / 16, B_), 256, 0, stream>>>(q, k, v, o);
}

// Round 5
// 146.534 us; speedup vs baseline: 2.1522x; 1.0535x over previous
//
#include <hip/hip_runtime.h>
#include <hip/hip_bf16.h>

#define B_ 8
#define C_ 64
#define H_ 128
#define W_ 128
#define HW_ (H_ * W_)

typedef __attribute__((ext_vector_type(8))) short short8;
typedef __attribute__((ext_vector_type(4))) float float4v;
typedef _Float16 f16x2 __attribute__((ext_vector_type(2)));

static __device__ inline unsigned bfbits(float f) {
    __hip_bfloat16 h = __float2bfloat16(f);
    unsigned short s;
    __builtin_memcpy(&s, &h, 2);
    return (unsigned)s;
}

// f16x2 pair-dot with f32 accumulate (v_dot2_f32_f16).
static __device__ inline float dot2(unsigned a, unsigned b, float c) {
    f16x2 ha, hb;
    __builtin_memcpy(&ha, &a, 4);
    __builtin_memcpy(&hb, &b, 4);
#if __has_builtin(__builtin_amdgcn_fdot2)
    return __builtin_amdgcn_fdot2(ha, hb, c, false);
#else
    return fmaf((float)ha.x, (float)hb.x, fmaf((float)ha.y, (float)hb.y, c));
#endif
}

static __device__ inline float2 up2(unsigned u) {
    f16x2 h;
    __builtin_memcpy(&h, &u, 4);
    return make_float2((float)h.x, (float)h.y);
}

// ---------------------------------------------------------------------------
// K0: repack W1|W2|W3 (fp32 [o][c]) into bf16 MFMA B-fragments, SPLIT hi/lo.
// ---------------------------------------------------------------------------
__global__ void repack_w(const float* __restrict__ w1, const float* __restrict__ w2,
                         const float* __restrict__ w3,
                         unsigned short* __restrict__ wBhi, unsigned short* __restrict__ wBlo)
{
    const int i = blockIdx.x * 256 + threadIdx.x;
    if (i >= 12288) return;
    const int j = i & 7, lane = (i >> 3) & 63, ks = (i >> 9) & 1, nt = i >> 10;
    const int o = nt * 16 + (lane & 15);
    const int c = ks * 32 + (lane >> 4) * 8 + j;
    const float* wsel = (o < 64) ? w1 : (o < 128) ? w2 : w3;
    const float w = wsel[(o & 63) * 64 + c];
    const unsigned hb = bfbits(w);
    wBhi[i] = (unsigned short)hb;
    wBlo[i] = (unsigned short)bfbits(w - __uint_as_float(hb << 16));
}

// ---------------------------------------------------------------------------
// K1: QKV projection — UNCHANGED from R4 (proven: rest-of-pipeline 105->61us).
// 512-thread blocks, 2m x 4n waves, 3 n-tiles/wave, launch_bounds(512,4)
// -> 4 waves/SIMD. 3-term bf16 split MFMA, fp32 accum. fp16 outputs.
// ---------------------------------------------------------------------------
__global__ __launch_bounds__(512, 4) void proj_qkv(
    const float* __restrict__ x,
    const unsigned short* __restrict__ wBhi, const unsigned short* __restrict__ wBlo,
    _Float16* __restrict__ q, _Float16* __restrict__ k, _Float16* __restrict__ v)
{
    const int b = blockIdx.y;
    const int px0 = blockIdx.x * 128;
    const int t = threadIdx.x;
    const int lane = t & 63;
    const int wave = t >> 6;                 // 0..7
    const int wave_m = wave & 1, wave_n = wave >> 1;   // 2 x 4
    const int n = lane & 15, kg = lane >> 4;

    float4v acc[3][4];
    #pragma unroll
    for (int tnt = 0; tnt < 3; ++tnt)
        #pragma unroll
        for (int mt = 0; mt < 4; ++mt)
            acc[tnt][mt] = (float4v){0.f, 0.f, 0.f, 0.f};

    const float* xb = x + (size_t)b * C_ * HW_;
    const int pxl = px0 + wave_m * 64 + n;

    #pragma unroll
    for (int ks = 0; ks < 2; ++ks) {
        short8 ahi[4], alo[4];
        #pragma unroll
        for (int mt = 0; mt < 4; ++mt) {
            #pragma unroll
            for (int j = 0; j < 8; ++j) {
                const int c = ks * 32 + kg * 8 + j;
                const float f = xb[(size_t)c * HW_ + pxl + mt * 16];
                const unsigned hb = bfbits(f);
                ahi[mt][j] = (short)hb;
                alo[mt][j] = (short)bfbits(f - __uint_as_float(hb << 16));
            }
        }
        #pragma unroll
        for (int tnt = 0; tnt < 3; ++tnt) {
            const int gnt = wave_n * 3 + tnt;          // 0..11 global n-tile
            const size_t bidx = (((size_t)gnt * 2 + ks) * 64 + lane) * 8;
            short8 bh, bl;
            {
                const uint4 uh = *(const uint4*)(wBhi + bidx);
                const uint4 ul = *(const uint4*)(wBlo + bidx);
                __builtin_memcpy(&bh, &uh, 16);
                __builtin_memcpy(&bl, &ul, 16);
            }
            #pragma unroll
            for (int mt = 0; mt < 4; ++mt) {
                acc[tnt][mt] = __builtin_amdgcn_mfma_f32_16x16x32_bf16(
                    ahi[mt], bh, acc[tnt][mt], 0, 0, 0);
                acc[tnt][mt] = __builtin_amdgcn_mfma_f32_16x16x32_bf16(
                    alo[mt], bh, acc[tnt][mt], 0, 0, 0);
                acc[tnt][mt] = __builtin_amdgcn_mfma_f32_16x16x32_bf16(
                    ahi[mt], bl, acc[tnt][mt], 0, 0, 0);
            }
        }
    }

    // epilogue: D col = n (output o), row m = kg*4 + reg (pixel); fp16 stores
    #pragma unroll
    for (int tnt = 0; tnt < 3; ++tnt) {
        const int gnt = wave_n * 3 + tnt;              // wave-uniform
        _Float16* base = (gnt < 4) ? q : (gnt < 8) ? k : v;
        const int chunk = gnt & 3;
        #pragma unroll
        for (int mt = 0; mt < 4; ++mt) {
            const int pxm = px0 + wave_m * 64 + mt * 16 + kg * 4;
            const float4v d = acc[tnt][mt];
            _Float16* p = base + (((size_t)b * 4 + chunk) * HW_ + pxm) * 16 + n;
            #pragma unroll
            for (int r = 0; r < 4; ++r) p[(size_t)r * 16] = (_Float16)d[r];
        }
    }
}

// ---------------------------------------------------------------------------
// K2: fused local attention — channel-split pair threads, 4 waves/SIMD.
// R4 lesson: identical source ran 55.7 or 93.5us depending on sibling-kernel
// codegen (rule #19) because 2 waves/SIMD has ZERO latency-hiding slack.
// Fix is structural TLP, not scheduler luck:
//   512 threads / 16x16 tile; lanes (2i,2i+1) share a pixel, split channels
//   (4 LDS planes each). Partial sc[49] over own planes -> one xor-1
//   butterfly per score (in-wave swizzle) -> duplicated softmax ->
//   phase-2 acc[32] over own planes. Total LDS reads / HBM bytes / FMA
//   UNCHANGED, spread over 16 waves/CU = 4/SIMD (2x TLP).
// Registers: peak ~100 live (qv16+sc49 / sc49+acc32) -- no spill, no
// two-pass hack. PL_=1948: 4*PL_ === 16 (mod 32) banks, so the pair-lane
// plane offset + row stride reproduces the proven {0,24,16,8} bank spread.
// LDS 62336 B, 2 blocks/CU (124.7KB/CU <= 160KB). grid (8,8,8) x 512 thr.
// ---------------------------------------------------------------------------
#define HP_ 484                 // 22*22 halo pixels
#define PL_ 1948                // words per uint4-plane (484*4 + 12 pad)

__global__ __launch_bounds__(512, 4) void local_attn(
    const _Float16* __restrict__ q, const _Float16* __restrict__ k,
    const _Float16* __restrict__ v, float* __restrict__ out)
{
    __shared__ float tile[8 * PL_];
    const int b = blockIdx.z, h0 = blockIdx.y * 16, w0 = blockIdx.x * 16;
    const int t = threadIdx.x;
    const int lane = t & 63, wave = t >> 6;
    const int g = lane & 1;                      // channel-group: planes g*4..g*4+3
    const int pixel = wave * 32 + (lane >> 1);   // 0..255
    const int pw = pixel & 15, ph = pixel >> 4;
    const size_t px = (size_t)(h0 + ph) * W_ + (w0 + pw);

    // q for own pixel, own 4 planes: 16 VGPR
    uint4 qv[4];
    #pragma unroll
    for (int pp = 0; pp < 4; ++pp) {
        const int p8 = g * 4 + pp;
        qv[pp] = *(const uint4*)(q + (((size_t)b * 4 + (p8 >> 1)) * HW_ + px) * 16 + (p8 & 1) * 8);
    }

    // ---- stage all of k (fp16, 8 planes), 512 threads ----
    for (int i = t; i < HP_ * 8; i += 512) {
        const int pix = i >> 3, c8 = i & 7;
        const int r = pix / 22, cl = pix - r * 22;
        const int gh = h0 + r - 3, gw = w0 + cl - 3;
        uint4 val = make_uint4(0u, 0u, 0u, 0u);
        if (gh >= 0 && gh < H_ && gw >= 0 && gw < W_)
            val = *(const uint4*)(k + (((size_t)b * 4 + (c8 >> 1)) * HW_ +
                                       (size_t)gh * W_ + gw) * 16 + (c8 & 1) * 8);
        *(uint4*)(tile + c8 * PL_ + pix * 4) = val;
    }
    __syncthreads();

    // ---- phase 1: partial scores over own 4 planes ----
    float sc[49];
    #pragma unroll
    for (int dh = 0; dh < 7; ++dh) {
        #pragma unroll
        for (int dw = 0; dw < 7; ++dw) {
            const int np = ((ph + dh) * 22 + (pw + dw)) * 4;
            float s0 = 0.f, s1 = 0.f, s2 = 0.f, s3 = 0.f;
            #pragma unroll
            for (int pp = 0; pp < 4; ++pp) {
                const uint4 u = *(const uint4*)(tile + (g * 4 + pp) * PL_ + np);
                s0 = dot2(qv[pp].x, u.x, s0);
                s1 = dot2(qv[pp].y, u.y, s1);
                s2 = dot2(qv[pp].z, u.z, s2);
                s3 = dot2(qv[pp].w, u.w, s3);
            }
            sc[dh * 7 + dw] = (s0 + s1) + (s2 + s3);
        }
    }

    // ---- merge pair partials: xor-1 butterfly (in-wave, 32-lane groups) ----
    #pragma unroll
    for (int i = 0; i < 49; ++i)
        sc[i] += __shfl_xor(sc[i], 1, 64);

    // ---- softmax over 49 (duplicated per pair — 49 extra exp, negligible) ----
    float m = sc[0];
    #pragma unroll
    for (int i = 1; i < 49; ++i) m = fmaxf(m, sc[i]);
    float s = 0.f;
    #pragma unroll
    for (int i = 0; i < 49; ++i) { sc[i] = __expf(sc[i] - m); s += sc[i]; }
    const float inv = 1.f / s;
    #pragma unroll
    for (int i = 0; i < 49; ++i) sc[i] *= inv;

    __syncthreads();            // all phase-1 reads done before overwrite

    // ---- stage all of v (fp16, same layout) ----
    for (int i = t; i < HP_ * 8; i += 512) {
        const int pix = i >> 3, c8 = i & 7;
        const int r = pix / 22, cl = pix - r * 22;
        const int gh = h0 + r - 3, gw = w0 + cl - 3;
        uint4 val = make_uint4(0u, 0u, 0u, 0u);
        if (gh >= 0 && gh < H_ && gw >= 0 && gw < W_)
            val = *(const uint4*)(v + (((size_t)b * 4 + (c8 >> 1)) * HW_ +
                                       (size_t)gh * W_ + gw) * 16 + (c8 & 1) * 8);
        *(uint4*)(tile + c8 * PL_ + pix * 4) = val;
    }
    __syncthreads();

    // ---- phase 2: weighting over own 4 planes (acc[32]) ----
    float acc[32];
    #pragma unroll
    for (int c = 0; c < 32; ++c) acc[c] = 0.f;
    #pragma unroll
    for (int dh = 0; dh < 7; ++dh) {
        #pragma unroll
        for (int dw = 0; dw < 7; ++dw) {
            const float wgt = sc[dh * 7 + dw];
            const int np = ((ph + dh) * 22 + (pw + dw)) * 4;
            #pragma unroll
            for (int pp = 0; pp < 4; ++pp) {
                const uint4 u = *(const uint4*)(tile + (g * 4 + pp) * PL_ + np);
                const int a = pp * 8;
                float2 f;
                f = up2(u.x); acc[a + 0] = fmaf(wgt, f.x, acc[a + 0]);
                              acc[a + 1] = fmaf(wgt, f.y, acc[a + 1]);
                f = up2(u.y); acc[a + 2] = fmaf(wgt, f.x, acc[a + 2]);
                              acc[a + 3] = fmaf(wgt, f.y, acc[a + 3]);
                f = up2(u.z); acc[a + 4] = fmaf(wgt, f.x, acc[a + 4]);
                              acc[a + 5] = fmaf(wgt, f.y, acc[a + 5]);
                f = up2(u.w); acc[a + 6] = fmaf(wgt, f.x, acc[a + 6]);
                              acc[a + 7] = fmaf(wgt, f.y, acc[a + 7]);
            }
        }
    }

    // ---- store own 32 channels: [b][64][HW] ----
    #pragma unroll
    for (int pp = 0; pp < 4; ++pp) {
        const int p8 = g * 4 + pp;
        const int ch0 = (p8 >> 1) * 16 + (p8 & 1) * 8;
        #pragma unroll
        for (int j = 0; j < 8; ++j)
            out[((size_t)b * 64 + ch0 + j) * HW_ + px] = acc[pp * 8 + j];
    }
}

extern "C" void kernel_launch(void* const* d_in, const int* in_sizes, int n_in,
                              void* d_out, int out_size, void* d_ws, size_t ws_size,
                              hipStream_t stream) {
    const float* x  = (const float*)d_in[0];
    const float* w1 = (const float*)d_in[1];
    const float* w2 = (const float*)d_in[2];
    const float* w3 = (const float*)d_in[3];

    const size_t NE = (size_t)B_ * 4 * HW_ * 16;   // 8388608 elems per tensor
    _Float16* q = (_Float16*)d_ws;
    _Float16* k = q + NE;
    _Float16* v = k + NE;
    unsigned short* wBhi = (unsigned short*)(v + NE);  // 12288 ushorts
    unsigned short* wBlo = wBhi + 12288;
    float* o = (float*)d_out;

    repack_w<<<dim3(48), 256, 0, stream>>>(w1, w2, w3, wBhi, wBlo);
    proj_qkv<<<dim3(HW_ / 128, B_), 512, 0, stream>>>(x, wBhi, wBlo, q, k, v);
    local_attn<<<dim3(W_ / 16, H_ / 16, B_), 512, 0, stream>>>(q, k, v, o);
}

// Round 6
// 142.577 us; speedup vs baseline: 2.2119x; 1.0278x over previous
//
#include <hip/hip_runtime.h>
#include <hip/hip_bf16.h>

#define B_ 8
#define C_ 64
#define H_ 128
#define W_ 128
#define HW_ (H_ * W_)

typedef __attribute__((ext_vector_type(8))) short short8;
typedef __attribute__((ext_vector_type(4))) float float4v;
typedef _Float16 f16x2 __attribute__((ext_vector_type(2)));

static __device__ inline unsigned bfbits(float f) {
    __hip_bfloat16 h = __float2bfloat16(f);
    unsigned short s;
    __builtin_memcpy(&s, &h, 2);
    return (unsigned)s;
}

// f16x2 pair-dot with f32 accumulate (v_dot2_f32_f16).
static __device__ inline float dot2(unsigned a, unsigned b, float c) {
    f16x2 ha, hb;
    __builtin_memcpy(&ha, &a, 4);
    __builtin_memcpy(&hb, &b, 4);
#if __has_builtin(__builtin_amdgcn_fdot2)
    return __builtin_amdgcn_fdot2(ha, hb, c, false);
#else
    return fmaf((float)ha.x, (float)hb.x, fmaf((float)ha.y, (float)hb.y, c));
#endif
}

static __device__ inline float2 up2(unsigned u) {
    f16x2 h;
    __builtin_memcpy(&h, &u, 4);
    return make_float2((float)h.x, (float)h.y);
}

// ---------------------------------------------------------------------------
// K0: repack W1|W2|W3 (fp32 [o][c]) into bf16 MFMA B-fragments, SPLIT hi/lo.
// ---------------------------------------------------------------------------
__global__ void repack_w(const float* __restrict__ w1, const float* __restrict__ w2,
                         const float* __restrict__ w3,
                         unsigned short* __restrict__ wBhi, unsigned short* __restrict__ wBlo)
{
    const int i = blockIdx.x * 256 + threadIdx.x;
    if (i >= 12288) return;
    const int j = i & 7, lane = (i >> 3) & 63, ks = (i >> 9) & 1, nt = i >> 10;
    const int o = nt * 16 + (lane & 15);
    const int c = ks * 32 + (lane >> 4) * 8 + j;
    const float* wsel = (o < 64) ? w1 : (o < 128) ? w2 : w3;
    const float w = wsel[(o & 63) * 64 + c];
    const unsigned hb = bfbits(w);
    wBhi[i] = (unsigned short)hb;
    wBlo[i] = (unsigned short)bfbits(w - __uint_as_float(hb << 16));
}

// ---------------------------------------------------------------------------
// K1: QKV projection. Same math (3-term bf16 split MFMA, fp32 accum), but x
// is now LDS-staged: 4 coalesced float4 loads/thread into a [px][68] fp32
// tile (34.8 KB), A-fragments then read as aligned b128 pairs (conflict-free:
// bank step 4/lane, 8 hits/bank/instr = b128 minimum). This replaces the 64
// scattered global dwords/thread (channel-strided, latency-bound under the
// 128-VGPR cap) with bulk loads + fast LDS reads. fp16 outputs unchanged.
// ---------------------------------------------------------------------------
#define XROW_ 68                 // padded row stride (words); 68*px ≡ 0 mod 4 (b128 align)

__global__ __launch_bounds__(512, 4) void proj_qkv(
    const float* __restrict__ x,
    const unsigned short* __restrict__ wBhi, const unsigned short* __restrict__ wBlo,
    _Float16* __restrict__ q, _Float16* __restrict__ k, _Float16* __restrict__ v)
{
    __shared__ float xt[128 * XROW_];
    const int b = blockIdx.y;
    const int px0 = blockIdx.x * 128;
    const int t = threadIdx.x;
    const int lane = t & 63;
    const int wave = t >> 6;                 // 0..7
    const int wave_m = wave & 1, wave_n = wave >> 1;   // 2 x 4
    const int n = lane & 15, kg = lane >> 4;

    // ---- stage x tile: [c][128px] global -> [px][ch] LDS (transposed) ----
    const float* xb = x + (size_t)b * C_ * HW_;
    #pragma unroll
    for (int r = 0; r < 4; ++r) {
        const int fi = t + r * 512;          // 2048 float4s total
        const int c = fi >> 5;               // 32 float4 per channel row
        const int p4 = (fi & 31) * 4;
        const float4 val = *(const float4*)(xb + (size_t)c * HW_ + px0 + p4);
        xt[(p4 + 0) * XROW_ + c] = val.x;
        xt[(p4 + 1) * XROW_ + c] = val.y;
        xt[(p4 + 2) * XROW_ + c] = val.z;
        xt[(p4 + 3) * XROW_ + c] = val.w;
    }
    __syncthreads();

    float4v acc[3][4];
    #pragma unroll
    for (int tnt = 0; tnt < 3; ++tnt)
        #pragma unroll
        for (int mt = 0; mt < 4; ++mt)
            acc[tnt][mt] = (float4v){0.f, 0.f, 0.f, 0.f};

    const int pxl = wave_m * 64 + n;         // local px base

    #pragma unroll
    for (int ks = 0; ks < 2; ++ks) {
        short8 ahi[4], alo[4];
        #pragma unroll
        for (int mt = 0; mt < 4; ++mt) {
            const float* xp = xt + (size_t)(pxl + mt * 16) * XROW_ + ks * 32 + kg * 8;
            const float4 xa = *(const float4*)xp;
            const float4 xc = *(const float4*)(xp + 4);
            const float xv[8] = {xa.x, xa.y, xa.z, xa.w, xc.x, xc.y, xc.z, xc.w};
            #pragma unroll
            for (int j = 0; j < 8; ++j) {
                const float f = xv[j];
                const unsigned hb = bfbits(f);
                ahi[mt][j] = (short)hb;
                alo[mt][j] = (short)bfbits(f - __uint_as_float(hb << 16));
            }
        }
        #pragma unroll
        for (int tnt = 0; tnt < 3; ++tnt) {
            const int gnt = wave_n * 3 + tnt;          // 0..11 global n-tile
            const size_t bidx = (((size_t)gnt * 2 + ks) * 64 + lane) * 8;
            short8 bh, bl;
            {
                const uint4 uh = *(const uint4*)(wBhi + bidx);
                const uint4 ul = *(const uint4*)(wBlo + bidx);
                __builtin_memcpy(&bh, &uh, 16);
                __builtin_memcpy(&bl, &ul, 16);
            }
            #pragma unroll
            for (int mt = 0; mt < 4; ++mt) {
                acc[tnt][mt] = __builtin_amdgcn_mfma_f32_16x16x32_bf16(
                    ahi[mt], bh, acc[tnt][mt], 0, 0, 0);
                acc[tnt][mt] = __builtin_amdgcn_mfma_f32_16x16x32_bf16(
                    alo[mt], bh, acc[tnt][mt], 0, 0, 0);
                acc[tnt][mt] = __builtin_amdgcn_mfma_f32_16x16x32_bf16(
                    ahi[mt], bl, acc[tnt][mt], 0, 0, 0);
            }
        }
    }

    // epilogue: D col = n (output o), row m = kg*4 + reg (pixel); fp16 stores
    #pragma unroll
    for (int tnt = 0; tnt < 3; ++tnt) {
        const int gnt = wave_n * 3 + tnt;              // wave-uniform
        _Float16* base = (gnt < 4) ? q : (gnt < 8) ? k : v;
        const int chunk = gnt & 3;
        #pragma unroll
        for (int mt = 0; mt < 4; ++mt) {
            const int pxm = px0 + wave_m * 64 + mt * 16 + kg * 4;
            const float4v d = acc[tnt][mt];
            _Float16* p = base + (((size_t)b * 4 + chunk) * HW_ + pxm) * 16 + n;
            #pragma unroll
            for (int r = 0; r < 4; ++r) p[(size_t)r * 16] = (_Float16)d[r];
        }
    }
}

// ---------------------------------------------------------------------------
// K2: fused local attention — channel-split pairs (R5 structure, 46.6us) +
// partial T14 async-stage for v: first half of the v-halo (vreg[4], 16 VGPR)
// is loaded BEFORE phase 1 (HBM/L2 latency flies under the score compute),
// written to LDS after the phase-1 barrier; second half stages normally.
// Peak live ≈ sc49 + qv16 + vreg16 + temps ≈ 110 < 128 — no spill (R1/R3
// lesson respected). Everything else identical to R5.
// ---------------------------------------------------------------------------
#define HP_ 484                 // 22*22 halo pixels
#define PL_ 1948                // words per uint4-plane (484*4 + 12 pad)

__global__ __launch_bounds__(512, 4) void local_attn(
    const _Float16* __restrict__ q, const _Float16* __restrict__ k,
    const _Float16* __restrict__ v, float* __restrict__ out)
{
    __shared__ float tile[8 * PL_];
    const int b = blockIdx.z, h0 = blockIdx.y * 16, w0 = blockIdx.x * 16;
    const int t = threadIdx.x;
    const int lane = t & 63, wave = t >> 6;
    const int g = lane & 1;                      // channel-group: planes g*4..g*4+3
    const int pixel = wave * 32 + (lane >> 1);   // 0..255
    const int pw = pixel & 15, ph = pixel >> 4;
    const size_t px = (size_t)(h0 + ph) * W_ + (w0 + pw);

    // q for own pixel, own 4 planes: 16 VGPR
    uint4 qv[4];
    #pragma unroll
    for (int pp = 0; pp < 4; ++pp) {
        const int p8 = g * 4 + pp;
        qv[pp] = *(const uint4*)(q + (((size_t)b * 4 + (p8 >> 1)) * HW_ + px) * 16 + (p8 & 1) * 8);
    }

    // ---- stage all of k (fp16, 8 planes), 512 threads ----
    for (int i = t; i < HP_ * 8; i += 512) {
        const int pix = i >> 3, c8 = i & 7;
        const int r = pix / 22, cl = pix - r * 22;
        const int gh = h0 + r - 3, gw = w0 + cl - 3;
        uint4 val = make_uint4(0u, 0u, 0u, 0u);
        if (gh >= 0 && gh < H_ && gw >= 0 && gw < W_)
            val = *(const uint4*)(k + (((size_t)b * 4 + (c8 >> 1)) * HW_ +
                                       (size_t)gh * W_ + gw) * 16 + (c8 & 1) * 8);
        *(uint4*)(tile + c8 * PL_ + pix * 4) = val;
    }
    __syncthreads();

    // ---- T14 issue-early: first half of v-halo into registers (16 VGPR) ----
    uint4 vreg[4];
    #pragma unroll
    for (int r = 0; r < 4; ++r) {
        const int i = t + r * 512;               // max 2047 < 3872, no range check
        const int pix = i >> 3, c8 = i & 7;
        const int rr = pix / 22, cl = pix - rr * 22;
        const int gh = h0 + rr - 3, gw = w0 + cl - 3;
        vreg[r] = make_uint4(0u, 0u, 0u, 0u);
        if (gh >= 0 && gh < H_ && gw >= 0 && gw < W_)
            vreg[r] = *(const uint4*)(v + (((size_t)b * 4 + (c8 >> 1)) * HW_ +
                                           (size_t)gh * W_ + gw) * 16 + (c8 & 1) * 8);
    }

    // ---- phase 1: partial scores over own 4 planes ----
    float sc[49];
    #pragma unroll
    for (int dh = 0; dh < 7; ++dh) {
        #pragma unroll
        for (int dw = 0; dw < 7; ++dw) {
            const int np = ((ph + dh) * 22 + (pw + dw)) * 4;
            float s0 = 0.f, s1 = 0.f, s2 = 0.f, s3 = 0.f;
            #pragma unroll
            for (int pp = 0; pp < 4; ++pp) {
                const uint4 u = *(const uint4*)(tile + (g * 4 + pp) * PL_ + np);
                s0 = dot2(qv[pp].x, u.x, s0);
                s1 = dot2(qv[pp].y, u.y, s1);
                s2 = dot2(qv[pp].z, u.z, s2);
                s3 = dot2(qv[pp].w, u.w, s3);
            }
            sc[dh * 7 + dw] = (s0 + s1) + (s2 + s3);
        }
    }

    // ---- merge pair partials: xor-1 butterfly (in-wave swizzle) ----
    #pragma unroll
    for (int i = 0; i < 49; ++i)
        sc[i] += __shfl_xor(sc[i], 1, 64);

    // ---- softmax over 49 (duplicated per pair) ----
    float m = sc[0];
    #pragma unroll
    for (int i = 1; i < 49; ++i) m = fmaxf(m, sc[i]);
    float s = 0.f;
    #pragma unroll
    for (int i = 0; i < 49; ++i) { sc[i] = __expf(sc[i] - m); s += sc[i]; }
    const float inv = 1.f / s;
    #pragma unroll
    for (int i = 0; i < 49; ++i) sc[i] *= inv;

    __syncthreads();            // all phase-1 reads done before overwrite

    // ---- write-late: first half of v from regs; second half loads now ----
    #pragma unroll
    for (int r = 0; r < 4; ++r) {
        const int i = t + r * 512;
        const int pix = i >> 3, c8 = i & 7;
        *(uint4*)(tile + c8 * PL_ + pix * 4) = vreg[r];
    }
    for (int i = t + 2048; i < HP_ * 8; i += 512) {
        const int pix = i >> 3, c8 = i & 7;
        const int r = pix / 22, cl = pix - r * 22;
        const int gh = h0 + r - 3, gw = w0 + cl - 3;
        uint4 val = make_uint4(0u, 0u, 0u, 0u);
        if (gh >= 0 && gh < H_ && gw >= 0 && gw < W_)
            val = *(const uint4*)(v + (((size_t)b * 4 + (c8 >> 1)) * HW_ +
                                       (size_t)gh * W_ + gw) * 16 + (c8 & 1) * 8);
        *(uint4*)(tile + c8 * PL_ + pix * 4) = val;
    }
    __syncthreads();

    // ---- phase 2: weighting over own 4 planes (acc[32]) ----
    float acc[32];
    #pragma unroll
    for (int c = 0; c < 32; ++c) acc[c] = 0.f;
    #pragma unroll
    for (int dh = 0; dh < 7; ++dh) {
        #pragma unroll
        for (int dw = 0; dw < 7; ++dw) {
            const float wgt = sc[dh * 7 + dw];
            const int np = ((ph + dh) * 22 + (pw + dw)) * 4;
            #pragma unroll
            for (int pp = 0; pp < 4; ++pp) {
                const uint4 u = *(const uint4*)(tile + (g * 4 + pp) * PL_ + np);
                const int a = pp * 8;
                float2 f;
                f = up2(u.x); acc[a + 0] = fmaf(wgt, f.x, acc[a + 0]);
                              acc[a + 1] = fmaf(wgt, f.y, acc[a + 1]);
                f = up2(u.y); acc[a + 2] = fmaf(wgt, f.x, acc[a + 2]);
                              acc[a + 3] = fmaf(wgt, f.y, acc[a + 3]);
                f = up2(u.z); acc[a + 4] = fmaf(wgt, f.x, acc[a + 4]);
                              acc[a + 5] = fmaf(wgt, f.y, acc[a + 5]);
                f = up2(u.w); acc[a + 6] = fmaf(wgt, f.x, acc[a + 6]);
                              acc[a + 7] = fmaf(wgt, f.y, acc[a + 7]);
            }
        }
    }

    // ---- store own 32 channels: [b][64][HW] ----
    #pragma unroll
    for (int pp = 0; pp < 4; ++pp) {
        const int p8 = g * 4 + pp;
        const int ch0 = (p8 >> 1) * 16 + (p8 & 1) * 8;
        #pragma unroll
        for (int j = 0; j < 8; ++j)
            out[((size_t)b * 64 + ch0 + j) * HW_ + px] = acc[pp * 8 + j];
    }
}

extern "C" void kernel_launch(void* const* d_in, const int* in_sizes, int n_in,
                              void* d_out, int out_size, void* d_ws, size_t ws_size,
                              hipStream_t stream) {
    const float* x  = (const float*)d_in[0];
    const float* w1 = (const float*)d_in[1];
    const float* w2 = (const float*)d_in[2];
    const float* w3 = (const float*)d_in[3];

    const size_t NE = (size_t)B_ * 4 * HW_ * 16;   // 8388608 elems per tensor
    _Float16* q = (_Float16*)d_ws;
    _Float16* k = q + NE;
    _Float16* v = k + NE;
    unsigned short* wBhi = (unsigned short*)(v + NE);  // 12288 ushorts
    unsigned short* wBlo = wBhi + 12288;
    float* o = (float*)d_out;

    repack_w<<<dim3(48), 256, 0, stream>>>(w1, w2, w3, wBhi, wBlo);
    proj_qkv<<<dim3(HW_ / 128, B_), 512, 0, stream>>>(x, wBhi, wBlo, q, k, v);
    local_attn<<<dim3(W_ / 16, H_ / 16, B_), 512, 0, stream>>>(q, k, v, o);
}

// Round 7
// 142.253 us; speedup vs baseline: 2.2170x; 1.0023x over previous
//
#include <hip/hip_runtime.h>
#include <hip/hip_bf16.h>

#define B_ 8
#define C_ 64
#define H_ 128
#define W_ 128
#define HW_ (H_ * W_)

typedef __attribute__((ext_vector_type(8))) _Float16 half8v;
typedef __attribute__((ext_vector_type(4))) float float4v;
typedef _Float16 f16x2 __attribute__((ext_vector_type(2)));

// f16x2 pair-dot with f32 accumulate (v_dot2_f32_f16).
static __device__ inline float dot2(unsigned a, unsigned b, float c) {
    f16x2 ha, hb;
    __builtin_memcpy(&ha, &a, 4);
    __builtin_memcpy(&hb, &b, 4);
#if __has_builtin(__builtin_amdgcn_fdot2)
    return __builtin_amdgcn_fdot2(ha, hb, c, false);
#else
    return fmaf((float)ha.x, (float)hb.x, fmaf((float)ha.y, (float)hb.y, c));
#endif
}

static __device__ inline float2 up2(unsigned u) {
    f16x2 h;
    __builtin_memcpy(&h, &u, 4);
    return make_float2((float)h.x, (float)h.y);
}

// ---------------------------------------------------------------------------
// K0: repack W1|W2|W3 (fp32 [o][c]) into SINGLE-fp16 MFMA B-fragments.
// fp16 W rounding err 2^-11 -> score err ~2.4e-4, two orders below the
// storage-dominated 0.031 absmax (R6 theory; watch absmax to verify).
// Index: wBf[((nt*2+ks)*64+lane)*8+j] = W[o=nt*16+(lane&15)][c=ks*32+(lane>>4)*8+j]
// ---------------------------------------------------------------------------
__global__ void repack_w(const float* __restrict__ w1, const float* __restrict__ w2,
                         const float* __restrict__ w3, _Float16* __restrict__ wBf)
{
    const int i = blockIdx.x * 256 + threadIdx.x;
    if (i >= 12288) return;
    const int j = i & 7, lane = (i >> 3) & 63, ks = (i >> 9) & 1, nt = i >> 10;
    const int o = nt * 16 + (lane & 15);
    const int c = ks * 32 + (lane >> 4) * 8 + j;
    const float* wsel = (o < 64) ? w1 : (o < 128) ? w2 : w3;
    wBf[i] = (_Float16)wsel[(o & 63) * 64 + c];
}

// ---------------------------------------------------------------------------
// K1: QKV projection, fp16 2-term: x*W = xh*W + xl*W with xh,xl fp16
// (x exact to ~2^-21), W single fp16. mfma_f32_16x16x32_f16, fp32 accum.
// vs the 3-term bf16 version: MFMA 72->48/wave, B-loads halved, less
// split VALU. x LDS-staged as in R6 ([px][68] fp32 tile, 34.8 KB).
// 512 thr, 2m x 4n waves, 3 n-tiles/wave, launch_bounds(512,4).
// fp16 outputs, layout [b][chunk4][HW][16].
// ---------------------------------------------------------------------------
#define XROW_ 68                 // padded row stride (words)

__global__ __launch_bounds__(512, 4) void proj_qkv(
    const float* __restrict__ x, const _Float16* __restrict__ wBf,
    _Float16* __restrict__ q, _Float16* __restrict__ k, _Float16* __restrict__ v)
{
    __shared__ float xt[128 * XROW_];
    const int b = blockIdx.y;
    const int px0 = blockIdx.x * 128;
    const int t = threadIdx.x;
    const int lane = t & 63;
    const int wave = t >> 6;                 // 0..7
    const int wave_m = wave & 1, wave_n = wave >> 1;   // 2 x 4
    const int n = lane & 15, kg = lane >> 4;

    // ---- stage x tile: [c][128px] global -> [px][ch] LDS (transposed) ----
    const float* xb = x + (size_t)b * C_ * HW_;
    #pragma unroll
    for (int r = 0; r < 4; ++r) {
        const int fi = t + r * 512;          // 2048 float4s total
        const int c = fi >> 5;               // 32 float4 per channel row
        const int p4 = (fi & 31) * 4;
        const float4 val = *(const float4*)(xb + (size_t)c * HW_ + px0 + p4);
        xt[(p4 + 0) * XROW_ + c] = val.x;
        xt[(p4 + 1) * XROW_ + c] = val.y;
        xt[(p4 + 2) * XROW_ + c] = val.z;
        xt[(p4 + 3) * XROW_ + c] = val.w;
    }
    __syncthreads();

    float4v acc[3][4];
    #pragma unroll
    for (int tnt = 0; tnt < 3; ++tnt)
        #pragma unroll
        for (int mt = 0; mt < 4; ++mt)
            acc[tnt][mt] = (float4v){0.f, 0.f, 0.f, 0.f};

    const int pxl = wave_m * 64 + n;         // local px base

    #pragma unroll
    for (int ks = 0; ks < 2; ++ks) {
        half8v ah[4], al[4];
        #pragma unroll
        for (int mt = 0; mt < 4; ++mt) {
            const float* xp = xt + (size_t)(pxl + mt * 16) * XROW_ + ks * 32 + kg * 8;
            const float4 xa = *(const float4*)xp;
            const float4 xc = *(const float4*)(xp + 4);
            const float xv[8] = {xa.x, xa.y, xa.z, xa.w, xc.x, xc.y, xc.z, xc.w};
            #pragma unroll
            for (int j = 0; j < 8; ++j) {
                const float f = xv[j];
                const _Float16 h = (_Float16)f;
                ah[mt][j] = h;
                al[mt][j] = (_Float16)(f - (float)h);
            }
        }
        #pragma unroll
        for (int tnt = 0; tnt < 3; ++tnt) {
            const int gnt = wave_n * 3 + tnt;          // 0..11 global n-tile
            const size_t bidx = (((size_t)gnt * 2 + ks) * 64 + lane) * 8;
            half8v bfr;
            {
                const uint4 u = *(const uint4*)(wBf + bidx);
                __builtin_memcpy(&bfr, &u, 16);
            }
            #pragma unroll
            for (int mt = 0; mt < 4; ++mt) {
                acc[tnt][mt] = __builtin_amdgcn_mfma_f32_16x16x32_f16(
                    ah[mt], bfr, acc[tnt][mt], 0, 0, 0);
                acc[tnt][mt] = __builtin_amdgcn_mfma_f32_16x16x32_f16(
                    al[mt], bfr, acc[tnt][mt], 0, 0, 0);
            }
        }
    }

    // epilogue: D col = n (output o), row m = kg*4 + reg (pixel); fp16 stores
    #pragma unroll
    for (int tnt = 0; tnt < 3; ++tnt) {
        const int gnt = wave_n * 3 + tnt;              // wave-uniform
        _Float16* base = (gnt < 4) ? q : (gnt < 8) ? k : v;
        const int chunk = gnt & 3;
        #pragma unroll
        for (int mt = 0; mt < 4; ++mt) {
            const int pxm = px0 + wave_m * 64 + mt * 16 + kg * 4;
            const float4v d = acc[tnt][mt];
            _Float16* p = base + (((size_t)b * 4 + chunk) * HW_ + pxm) * 16 + n;
            #pragma unroll
            for (int r = 0; r < 4; ++r) p[(size_t)r * 16] = (_Float16)d[r];
        }
    }
}

// ---------------------------------------------------------------------------
// K2: fused local attention — channel-split pairs (R5 structure) + T14
// v-prefetch extended to 6 of 8 staging rounds (24 VGPR; rounds 0-5 have
// max index 3071 < 3872 so no bounds check; rounds 6-7 stage late).
// Live ≈ sc49 + qv16 + vreg24 + temps ≈ 110 < 128 — no spill.
// ---------------------------------------------------------------------------
#define HP_ 484                 // 22*22 halo pixels
#define PL_ 1948                // words per uint4-plane (484*4 + 12 pad)

__global__ __launch_bounds__(512, 4) void local_attn(
    const _Float16* __restrict__ q, const _Float16* __restrict__ k,
    const _Float16* __restrict__ v, float* __restrict__ out)
{
    __shared__ float tile[8 * PL_];
    const int b = blockIdx.z, h0 = blockIdx.y * 16, w0 = blockIdx.x * 16;
    const int t = threadIdx.x;
    const int lane = t & 63, wave = t >> 6;
    const int g = lane & 1;                      // channel-group: planes g*4..g*4+3
    const int pixel = wave * 32 + (lane >> 1);   // 0..255
    const int pw = pixel & 15, ph = pixel >> 4;
    const size_t px = (size_t)(h0 + ph) * W_ + (w0 + pw);

    // q for own pixel, own 4 planes: 16 VGPR
    uint4 qv[4];
    #pragma unroll
    for (int pp = 0; pp < 4; ++pp) {
        const int p8 = g * 4 + pp;
        qv[pp] = *(const uint4*)(q + (((size_t)b * 4 + (p8 >> 1)) * HW_ + px) * 16 + (p8 & 1) * 8);
    }

    // ---- stage all of k (fp16, 8 planes), 512 threads ----
    for (int i = t; i < HP_ * 8; i += 512) {
        const int pix = i >> 3, c8 = i & 7;
        const int r = pix / 22, cl = pix - r * 22;
        const int gh = h0 + r - 3, gw = w0 + cl - 3;
        uint4 val = make_uint4(0u, 0u, 0u, 0u);
        if (gh >= 0 && gh < H_ && gw >= 0 && gw < W_)
            val = *(const uint4*)(k + (((size_t)b * 4 + (c8 >> 1)) * HW_ +
                                       (size_t)gh * W_ + gw) * 16 + (c8 & 1) * 8);
        *(uint4*)(tile + c8 * PL_ + pix * 4) = val;
    }
    __syncthreads();

    // ---- T14 issue-early: 6/8 of v-halo into registers (24 VGPR) ----
    uint4 vreg[6];
    #pragma unroll
    for (int r = 0; r < 6; ++r) {
        const int i = t + r * 512;               // max 3071 < 3872, no range check
        const int pix = i >> 3, c8 = i & 7;
        const int rr = pix / 22, cl = pix - rr * 22;
        const int gh = h0 + rr - 3, gw = w0 + cl - 3;
        vreg[r] = make_uint4(0u, 0u, 0u, 0u);
        if (gh >= 0 && gh < H_ && gw >= 0 && gw < W_)
            vreg[r] = *(const uint4*)(v + (((size_t)b * 4 + (c8 >> 1)) * HW_ +
                                           (size_t)gh * W_ + gw) * 16 + (c8 & 1) * 8);
    }

    // ---- phase 1: partial scores over own 4 planes ----
    float sc[49];
    #pragma unroll
    for (int dh = 0; dh < 7; ++dh) {
        #pragma unroll
        for (int dw = 0; dw < 7; ++dw) {
            const int np = ((ph + dh) * 22 + (pw + dw)) * 4;
            float s0 = 0.f, s1 = 0.f, s2 = 0.f, s3 = 0.f;
            #pragma unroll
            for (int pp = 0; pp < 4; ++pp) {
                const uint4 u = *(const uint4*)(tile + (g * 4 + pp) * PL_ + np);
                s0 = dot2(qv[pp].x, u.x, s0);
                s1 = dot2(qv[pp].y, u.y, s1);
                s2 = dot2(qv[pp].z, u.z, s2);
                s3 = dot2(qv[pp].w, u.w, s3);
            }
            sc[dh * 7 + dw] = (s0 + s1) + (s2 + s3);
        }
    }

    // ---- merge pair partials: xor-1 butterfly (in-wave swizzle) ----
    #pragma unroll
    for (int i = 0; i < 49; ++i)
        sc[i] += __shfl_xor(sc[i], 1, 64);

    // ---- softmax over 49 (duplicated per pair) ----
    float m = sc[0];
    #pragma unroll
    for (int i = 1; i < 49; ++i) m = fmaxf(m, sc[i]);
    float s = 0.f;
    #pragma unroll
    for (int i = 0; i < 49; ++i) { sc[i] = __expf(sc[i] - m); s += sc[i]; }
    const float inv = 1.f / s;
    #pragma unroll
    for (int i = 0; i < 49; ++i) sc[i] *= inv;

    __syncthreads();            // all phase-1 reads done before overwrite

    // ---- write-late: 6 prefetched rounds from regs; last 2 load now ----
    #pragma unroll
    for (int r = 0; r < 6; ++r) {
        const int i = t + r * 512;
        const int pix = i >> 3, c8 = i & 7;
        *(uint4*)(tile + c8 * PL_ + pix * 4) = vreg[r];
    }
    for (int i = t + 3072; i < HP_ * 8; i += 512) {
        const int pix = i >> 3, c8 = i & 7;
        const int r = pix / 22, cl = pix - r * 22;
        const int gh = h0 + r - 3, gw = w0 + cl - 3;
        uint4 val = make_uint4(0u, 0u, 0u, 0u);
        if (gh >= 0 && gh < H_ && gw >= 0 && gw < W_)
            val = *(const uint4*)(v + (((size_t)b * 4 + (c8 >> 1)) * HW_ +
                                       (size_t)gh * W_ + gw) * 16 + (c8 & 1) * 8);
        *(uint4*)(tile + c8 * PL_ + pix * 4) = val;
    }
    __syncthreads();

    // ---- phase 2: weighting over own 4 planes (acc[32]) ----
    float acc[32];
    #pragma unroll
    for (int c = 0; c < 32; ++c) acc[c] = 0.f;
    #pragma unroll
    for (int dh = 0; dh < 7; ++dh) {
        #pragma unroll
        for (int dw = 0; dw < 7; ++dw) {
            const float wgt = sc[dh * 7 + dw];
            const int np = ((ph + dh) * 22 + (pw + dw)) * 4;
            #pragma unroll
            for (int pp = 0; pp < 4; ++pp) {
                const uint4 u = *(const uint4*)(tile + (g * 4 + pp) * PL_ + np);
                const int a = pp * 8;
                float2 f;
                f = up2(u.x); acc[a + 0] = fmaf(wgt, f.x, acc[a + 0]);
                              acc[a + 1] = fmaf(wgt, f.y, acc[a + 1]);
                f = up2(u.y); acc[a + 2] = fmaf(wgt, f.x, acc[a + 2]);
                              acc[a + 3] = fmaf(wgt, f.y, acc[a + 3]);
                f = up2(u.z); acc[a + 4] = fmaf(wgt, f.x, acc[a + 4]);
                              acc[a + 5] = fmaf(wgt, f.y, acc[a + 5]);
                f = up2(u.w); acc[a + 6] = fmaf(wgt, f.x, acc[a + 6]);
                              acc[a + 7] = fmaf(wgt, f.y, acc[a + 7]);
            }
        }
    }

    // ---- store own 32 channels: [b][64][HW] ----
    #pragma unroll
    for (int pp = 0; pp < 4; ++pp) {
        const int p8 = g * 4 + pp;
        const int ch0 = (p8 >> 1) * 16 + (p8 & 1) * 8;
        #pragma unroll
        for (int j = 0; j < 8; ++j)
            out[((size_t)b * 64 + ch0 + j) * HW_ + px] = acc[pp * 8 + j];
    }
}

extern "C" void kernel_launch(void* const* d_in, const int* in_sizes, int n_in,
                              void* d_out, int out_size, void* d_ws, size_t ws_size,
                              hipStream_t stream) {
    const float* x  = (const float*)d_in[0];
    const float* w1 = (const float*)d_in[1];
    const float* w2 = (const float*)d_in[2];
    const float* w3 = (const float*)d_in[3];

    const size_t NE = (size_t)B_ * 4 * HW_ * 16;   // 8388608 elems per tensor
    _Float16* q = (_Float16*)d_ws;
    _Float16* k = q + NE;
    _Float16* v = k + NE;
    _Float16* wBf = v + NE;                        // 12288 fp16
    float* o = (float*)d_out;

    repack_w<<<dim3(48), 256, 0, stream>>>(w1, w2, w3, wBf);
    proj_qkv<<<dim3(HW_ / 128, B_), 512, 0, stream>>>(x, wBf, q, k, v);
    local_attn<<<dim3(W_ / 16, H_ / 16, B_), 512, 0, stream>>>(q, k, v, o);
}

// Round 8
// 139.858 us; speedup vs baseline: 2.2549x; 1.0171x over previous
//
#include <hip/hip_runtime.h>
#include <hip/hip_bf16.h>

#define B_ 8
#define C_ 64
#define H_ 128
#define W_ 128
#define HW_ (H_ * W_)

typedef __attribute__((ext_vector_type(8))) _Float16 half8v;
typedef __attribute__((ext_vector_type(4))) float float4v;
typedef _Float16 f16x2 __attribute__((ext_vector_type(2)));

// f16x2 pair-dot with f32 accumulate (v_dot2_f32_f16).
static __device__ inline float dot2(unsigned a, unsigned b, float c) {
    f16x2 ha, hb;
    __builtin_memcpy(&ha, &a, 4);
    __builtin_memcpy(&hb, &b, 4);
#if __has_builtin(__builtin_amdgcn_fdot2)
    return __builtin_amdgcn_fdot2(ha, hb, c, false);
#else
    return fmaf((float)ha.x, (float)hb.x, fmaf((float)ha.y, (float)hb.y, c));
#endif
}

static __device__ inline float2 up2(unsigned u) {
    f16x2 h;
    __builtin_memcpy(&h, &u, 4);
    return make_float2((float)h.x, (float)h.y);
}

// ---------------------------------------------------------------------------
// K1: QKV projection, fp16 2-term (x = xh + xl, W single fp16), with the
// MFMA operands SWAPPED: acc = mfma(W_frag, x_frag) computes D[o][px]
// (A and B fragments share the same lane->(idx,k) mapping, so the same
// fragment builds serve both roles). D col = pixel, row = channel =>
// each thread's 4 acc values are 4 CONSECUTIVE channels of one pixel =
// one 8-B uint2 store; per-wave stores cover 512 contiguous bytes.
// Store count 48 scalar -> 12 x 8B coalesced (R7 theory: proj is
// store-bound; loads/MFMA/occupancy fixes all moved nothing).
// W fragments are loaded directly from w1/w2/w3 (L2-resident 48 KB) and
// converted inline -- repack_w dispatch eliminated.
// x LDS-staged as [px][68] fp32 tile. 512 thr, 2m x 4n waves, 3 n-tiles.
// fp16 outputs, layout [b][chunk4][HW][16] (unchanged for attn).
// ---------------------------------------------------------------------------
#define XROW_ 68                 // padded row stride (words)

__global__ __launch_bounds__(512, 4) void proj_qkv(
    const float* __restrict__ x,
    const float* __restrict__ w1, const float* __restrict__ w2,
    const float* __restrict__ w3,
    _Float16* __restrict__ q, _Float16* __restrict__ k, _Float16* __restrict__ v)
{
    __shared__ float xt[128 * XROW_];
    const int b = blockIdx.y;
    const int px0 = blockIdx.x * 128;
    const int t = threadIdx.x;
    const int lane = t & 63;
    const int wave = t >> 6;                 // 0..7
    const int wave_m = wave & 1, wave_n = wave >> 1;   // 2 x 4
    const int n = lane & 15, kg = lane >> 4;

    // ---- stage x tile: [c][128px] global -> [px][ch] LDS (transposed) ----
    const float* xb = x + (size_t)b * C_ * HW_;
    #pragma unroll
    for (int r = 0; r < 4; ++r) {
        const int fi = t + r * 512;          // 2048 float4s total
        const int c = fi >> 5;               // 32 float4 per channel row
        const int p4 = (fi & 31) * 4;
        const float4 val = *(const float4*)(xb + (size_t)c * HW_ + px0 + p4);
        xt[(p4 + 0) * XROW_ + c] = val.x;
        xt[(p4 + 1) * XROW_ + c] = val.y;
        xt[(p4 + 2) * XROW_ + c] = val.z;
        xt[(p4 + 3) * XROW_ + c] = val.w;
    }
    __syncthreads();

    float4v acc[3][4];
    #pragma unroll
    for (int tnt = 0; tnt < 3; ++tnt)
        #pragma unroll
        for (int mt = 0; mt < 4; ++mt)
            acc[tnt][mt] = (float4v){0.f, 0.f, 0.f, 0.f};

    const int pxl = wave_m * 64 + n;         // local px base

    #pragma unroll
    for (int ks = 0; ks < 2; ++ks) {
        half8v ah[4], al[4];
        #pragma unroll
        for (int mt = 0; mt < 4; ++mt) {
            const float* xp = xt + (size_t)(pxl + mt * 16) * XROW_ + ks * 32 + kg * 8;
            const float4 xa = *(const float4*)xp;
            const float4 xc = *(const float4*)(xp + 4);
            const float xv[8] = {xa.x, xa.y, xa.z, xa.w, xc.x, xc.y, xc.z, xc.w};
            #pragma unroll
            for (int j = 0; j < 8; ++j) {
                const float f = xv[j];
                const _Float16 h = (_Float16)f;
                ah[mt][j] = h;
                al[mt][j] = (_Float16)(f - (float)h);
            }
        }
        // W fragments for this ks: o = (gnt&3)*16 + n of wsel, c = ks*32+kg*8+j
        half8v wfr[3];
        #pragma unroll
        for (int tnt = 0; tnt < 3; ++tnt) {
            const int gnt = wave_n * 3 + tnt;
            const float* wsel = (gnt < 4) ? w1 : (gnt < 8) ? w2 : w3;
            const float* wrow = wsel + ((gnt & 3) * 16 + n) * 64 + ks * 32 + kg * 8;
            const float4 wa = *(const float4*)wrow;
            const float4 wc = *(const float4*)(wrow + 4);
            wfr[tnt][0] = (_Float16)wa.x; wfr[tnt][1] = (_Float16)wa.y;
            wfr[tnt][2] = (_Float16)wa.z; wfr[tnt][3] = (_Float16)wa.w;
            wfr[tnt][4] = (_Float16)wc.x; wfr[tnt][5] = (_Float16)wc.y;
            wfr[tnt][6] = (_Float16)wc.z; wfr[tnt][7] = (_Float16)wc.w;
        }
        #pragma unroll
        for (int tnt = 0; tnt < 3; ++tnt) {
            #pragma unroll
            for (int mt = 0; mt < 4; ++mt) {
                acc[tnt][mt] = __builtin_amdgcn_mfma_f32_16x16x32_f16(
                    wfr[tnt], ah[mt], acc[tnt][mt], 0, 0, 0);
                acc[tnt][mt] = __builtin_amdgcn_mfma_f32_16x16x32_f16(
                    wfr[tnt], al[mt], acc[tnt][mt], 0, 0, 0);
            }
        }
    }

    // epilogue (transposed D): col = n = pixel, row = kg*4+r = channel.
    // 4 consecutive channels of one pixel -> one 8-B uint2 store.
    #pragma unroll
    for (int tnt = 0; tnt < 3; ++tnt) {
        const int gnt = wave_n * 3 + tnt;              // wave-uniform
        _Float16* base = (gnt < 4) ? q : (gnt < 8) ? k : v;
        const int chunk = gnt & 3;
        #pragma unroll
        for (int mt = 0; mt < 4; ++mt) {
            const int pxm = px0 + wave_m * 64 + mt * 16 + n;
            const float4v d = acc[tnt][mt];
            f16x2 lo = {(_Float16)d[0], (_Float16)d[1]};
            f16x2 hi = {(_Float16)d[2], (_Float16)d[3]};
            uint2 u;
            __builtin_memcpy(&u.x, &lo, 4);
            __builtin_memcpy(&u.y, &hi, 4);
            *(uint2*)(base + (((size_t)b * 4 + chunk) * HW_ + pxm) * 16 + kg * 4) = u;
        }
    }
}

// ---------------------------------------------------------------------------
// K2: fused local attention — UNCHANGED from R7 (44.5 us, stable).
// Channel-split pairs, 512 thr, 4 waves/SIMD; single resident fp16 tile;
// dot2 scores + xor-1 merge; T14 v-prefetch 6/8 rounds.
// ---------------------------------------------------------------------------
#define HP_ 484                 // 22*22 halo pixels
#define PL_ 1948                // words per uint4-plane (484*4 + 12 pad)

__global__ __launch_bounds__(512, 4) void local_attn(
    const _Float16* __restrict__ q, const _Float16* __restrict__ k,
    const _Float16* __restrict__ v, float* __restrict__ out)
{
    __shared__ float tile[8 * PL_];
    const int b = blockIdx.z, h0 = blockIdx.y * 16, w0 = blockIdx.x * 16;
    const int t = threadIdx.x;
    const int lane = t & 63, wave = t >> 6;
    const int g = lane & 1;                      // channel-group: planes g*4..g*4+3
    const int pixel = wave * 32 + (lane >> 1);   // 0..255
    const int pw = pixel & 15, ph = pixel >> 4;
    const size_t px = (size_t)(h0 + ph) * W_ + (w0 + pw);

    // q for own pixel, own 4 planes: 16 VGPR
    uint4 qv[4];
    #pragma unroll
    for (int pp = 0; pp < 4; ++pp) {
        const int p8 = g * 4 + pp;
        qv[pp] = *(const uint4*)(q + (((size_t)b * 4 + (p8 >> 1)) * HW_ + px) * 16 + (p8 & 1) * 8);
    }

    // ---- stage all of k (fp16, 8 planes), 512 threads ----
    for (int i = t; i < HP_ * 8; i += 512) {
        const int pix = i >> 3, c8 = i & 7;
        const int r = pix / 22, cl = pix - r * 22;
        const int gh = h0 + r - 3, gw = w0 + cl - 3;
        uint4 val = make_uint4(0u, 0u, 0u, 0u);
        if (gh >= 0 && gh < H_ && gw >= 0 && gw < W_)
            val = *(const uint4*)(k + (((size_t)b * 4 + (c8 >> 1)) * HW_ +
                                       (size_t)gh * W_ + gw) * 16 + (c8 & 1) * 8);
        *(uint4*)(tile + c8 * PL_ + pix * 4) = val;
    }
    __syncthreads();

    // ---- T14 issue-early: 6/8 of v-halo into registers (24 VGPR) ----
    uint4 vreg[6];
    #pragma unroll
    for (int r = 0; r < 6; ++r) {
        const int i = t + r * 512;               // max 3071 < 3872, no range check
        const int pix = i >> 3, c8 = i & 7;
        const int rr = pix / 22, cl = pix - rr * 22;
        const int gh = h0 + rr - 3, gw = w0 + cl - 3;
        vreg[r] = make_uint4(0u, 0u, 0u, 0u);
        if (gh >= 0 && gh < H_ && gw >= 0 && gw < W_)
            vreg[r] = *(const uint4*)(v + (((size_t)b * 4 + (c8 >> 1)) * HW_ +
                                           (size_t)gh * W_ + gw) * 16 + (c8 & 1) * 8);
    }

    // ---- phase 1: partial scores over own 4 planes ----
    float sc[49];
    #pragma unroll
    for (int dh = 0; dh < 7; ++dh) {
        #pragma unroll
        for (int dw = 0; dw < 7; ++dw) {
            const int np = ((ph + dh) * 22 + (pw + dw)) * 4;
            float s0 = 0.f, s1 = 0.f, s2 = 0.f, s3 = 0.f;
            #pragma unroll
            for (int pp = 0; pp < 4; ++pp) {
                const uint4 u = *(const uint4*)(tile + (g * 4 + pp) * PL_ + np);
                s0 = dot2(qv[pp].x, u.x, s0);
                s1 = dot2(qv[pp].y, u.y, s1);
                s2 = dot2(qv[pp].z, u.z, s2);
                s3 = dot2(qv[pp].w, u.w, s3);
            }
            sc[dh * 7 + dw] = (s0 + s1) + (s2 + s3);
        }
    }

    // ---- merge pair partials: xor-1 butterfly (in-wave swizzle) ----
    #pragma unroll
    for (int i = 0; i < 49; ++i)
        sc[i] += __shfl_xor(sc[i], 1, 64);

    // ---- softmax over 49 (duplicated per pair) ----
    float m = sc[0];
    #pragma unroll
    for (int i = 1; i < 49; ++i) m = fmaxf(m, sc[i]);
    float s = 0.f;
    #pragma unroll
    for (int i = 0; i < 49; ++i) { sc[i] = __expf(sc[i] - m); s += sc[i]; }
    const float inv = 1.f / s;
    #pragma unroll
    for (int i = 0; i < 49; ++i) sc[i] *= inv;

    __syncthreads();            // all phase-1 reads done before overwrite

    // ---- write-late: 6 prefetched rounds from regs; last 2 load now ----
    #pragma unroll
    for (int r = 0; r < 6; ++r) {
        const int i = t + r * 512;
        const int pix = i >> 3, c8 = i & 7;
        *(uint4*)(tile + c8 * PL_ + pix * 4) = vreg[r];
    }
    for (int i = t + 3072; i < HP_ * 8; i += 512) {
        const int pix = i >> 3, c8 = i & 7;
        const int r = pix / 22, cl = pix - r * 22;
        const int gh = h0 + r - 3, gw = w0 + cl - 3;
        uint4 val = make_uint4(0u, 0u, 0u, 0u);
        if (gh >= 0 && gh < H_ && gw >= 0 && gw < W_)
            val = *(const uint4*)(v + (((size_t)b * 4 + (c8 >> 1)) * HW_ +
                                       (size_t)gh * W_ + gw) * 16 + (c8 & 1) * 8);
        *(uint4*)(tile + c8 * PL_ + pix * 4) = val;
    }
    __syncthreads();

    // ---- phase 2: weighting over own 4 planes (acc[32]) ----
    float acc[32];
    #pragma unroll
    for (int c = 0; c < 32; ++c) acc[c] = 0.f;
    #pragma unroll
    for (int dh = 0; dh < 7; ++dh) {
        #pragma unroll
        for (int dw = 0; dw < 7; ++dw) {
            const float wgt = sc[dh * 7 + dw];
            const int np = ((ph + dh) * 22 + (pw + dw)) * 4;
            #pragma unroll
            for (int pp = 0; pp < 4; ++pp) {
                const uint4 u = *(const uint4*)(tile + (g * 4 + pp) * PL_ + np);
                const int a = pp * 8;
                float2 f;
                f = up2(u.x); acc[a + 0] = fmaf(wgt, f.x, acc[a + 0]);
                              acc[a + 1] = fmaf(wgt, f.y, acc[a + 1]);
                f = up2(u.y); acc[a + 2] = fmaf(wgt, f.x, acc[a + 2]);
                              acc[a + 3] = fmaf(wgt, f.y, acc[a + 3]);
                f = up2(u.z); acc[a + 4] = fmaf(wgt, f.x, acc[a + 4]);
                              acc[a + 5] = fmaf(wgt, f.y, acc[a + 5]);
                f = up2(u.w); acc[a + 6] = fmaf(wgt, f.x, acc[a + 6]);
                              acc[a + 7] = fmaf(wgt, f.y, acc[a + 7]);
            }
        }
    }

    // ---- store own 32 channels: [b][64][HW] ----
    #pragma unroll
    for (int pp = 0; pp < 4; ++pp) {
        const int p8 = g * 4 + pp;
        const int ch0 = (p8 >> 1) * 16 + (p8 & 1) * 8;
        #pragma unroll
        for (int j = 0; j < 8; ++j)
            out[((size_t)b * 64 + ch0 + j) * HW_ + px] = acc[pp * 8 + j];
    }
}

extern "C" void kernel_launch(void* const* d_in, const int* in_sizes, int n_in,
                              void* d_out, int out_size, void* d_ws, size_t ws_size,
                              hipStream_t stream) {
    const float* x  = (const float*)d_in[0];
    const float* w1 = (const float*)d_in[1];
    const float* w2 = (const float*)d_in[2];
    const float* w3 = (const float*)d_in[3];

    const size_t NE = (size_t)B_ * 4 * HW_ * 16;   // 8388608 elems per tensor
    _Float16* q = (_Float16*)d_ws;
    _Float16* k = q + NE;
    _Float16* v = k + NE;
    float* o = (float*)d_out;

    proj_qkv<<<dim3(HW_ / 128, B_), 512, 0, stream>>>(x, w1, w2, w3, q, k, v);
    local_attn<<<dim3(W_ / 16, H_ / 16, B_), 512, 0, stream>>>(q, k, v, o);
}